// Round 16
// baseline (29.532 us; speedup 1.0000x reference)
//
#include <hip/hip_runtime.h>

#define NSAMP 2048
#define NCONF 128
#define NMO   64
#define NE    16   // electrons per spin (matrix dim)

typedef float v2f __attribute__((ext_vector_type(2)));

// Block = 256 threads = 2 samples x 128 configs.
// LDS: samples staged TRANSPOSED (column-major per (sample,spin) plane) with
// XOR swizzle on the 16B slot: word(c,r)=c*16+(((r>>2)^h(c))<<2)|(r&3),
// h(c)=(c^(c>>2))&3. One matrix column = 4 x ds_read_b128.
// (Staging/gather/cidx/(256,1) byte-identical to rounds 13/15.)
//
// Per thread: det(up)*det(dn) via LEFT-LOOKING UNPIVOTED LU (Crout) in
// 2-COLUMN PANELS, packed fp32 (v_pk_fma_f32):
//  * columns (2t,2t+1) loaded together (8 ds_read_b128, deeper load queue);
//  * each L2[k][m] read serves BOTH columns (L-read stream halves, 708->336)
//    and the two forward-sub chains are independent (2x ILP);
//  * in-pair apply of column j0 to j1 reuses a2[m]*r0 from VGPRs -> L
//    columns 14,15 never stored: L2 is 14x8 v2f, so adding b2 (+16 regs)
//    is NET-ZERO live-set change vs round 15 (the spill-cliff lesson of
//    rounds 7/8/9: only register-neutral restructures survive).
// Dead-slot discipline (as round 15): full-pair updates; every corrupted
// slot had its multiplier extracted beforehand and holds finite garbage.
__global__ __launch_bounds__(256, 1)
void SlaterPooling_45543833207162_kernel(const float* __restrict__ x,
                                         const int*   __restrict__ cup,
                                         const int*   __restrict__ cdn,
                                         float*       __restrict__ out) {
  __shared__ float tile[4 * 64 * NE];   // 4 planes x 64 cols x 16 rows = 16 KB
  float4* tile4 = reinterpret_cast<float4*>(tile);

  // ---- stage 16 KB coalesced; write transposed + swizzled ----
  {
    const float4* src = reinterpret_cast<const float4*>(
        x + (size_t)blockIdx.x * 2 * (2 * NE * NMO));
#pragma unroll
    for (int k = 0; k < 4; ++k) {
      const int   f4 = threadIdx.x + k * 256;   // float4 index in block region
      const float4 v = src[f4];
      const int flat  = f4 * 4;                 // word index (row-major global)
      const int plane = flat >> 10;             // (s_local, spin) plane 0..3
      const int r     = (flat >> 6) & 15;       // row within plane
      const int c4    = (flat >> 2) & 15;       // c = 4*c4 + d
      const int rlo = r & 3, rhi = r >> 2;
      const float vv[4] = {v.x, v.y, v.z, v.w};
#pragma unroll
      for (int d = 0; d < 4; ++d) {
        const int cc = 4 * c4 + d;
        const int h  = (d ^ c4) & 3;            // == (cc ^ (cc>>2)) & 3
        tile[plane * 1024 + cc * NE + (((rhi ^ h) << 2) | rlo)] = vv[d];
      }
    }
  }
  __syncthreads();

  const int s_local = threadIdx.x >> 7;         // 0..1
  const int c       = threadIdx.x & 127;        // config index
  float result = 1.0f;

  // spin loop NOT unrolled: L2 and panel regs reused across spins
#pragma unroll 1
  for (int spin = 0; spin < 2; ++spin) {
    // ---- config indices: 4 x int4, hoisted out of the column loop ----
    const int4* cfg4 = reinterpret_cast<const int4*>(
        (spin ? cdn : cup) + c * NE);
    const int4 q0 = cfg4[0], q1 = cfg4[1], q2 = cfg4[2], q3 = cfg4[3];
    const int cidx[16] = {q0.x, q0.y, q0.z, q0.w,  q1.x, q1.y, q1.z, q1.w,
                          q2.x, q2.y, q2.z, q2.w,  q3.x, q3.y, q3.z, q3.w};

    const float4* plane4 = tile4 + (s_local * 2 + spin) * 256;

    v2f L2[NE - 2][8];   // L columns 0..13 (14,15 never needed after pair)
    float det = 1.0f;    // no pivoting -> no sign correction

#pragma unroll
    for (int t = 0; t < 8; ++t) {
      const int j0 = 2 * t, j1 = 2 * t + 1;

      // ---- load panel columns j0 -> a2, j1 -> b2 (8 x ds_read_b128) ----
      v2f a2[8], b2[8];
      {
        const int cj = cidx[j0];
        const int h  = (cj ^ (cj >> 2)) & 3;
        const float4* col = plane4 + cj * 4;
        { const float4 v = col[0 ^ h]; a2[0] = v2f{v.x, v.y}; a2[1] = v2f{v.z, v.w}; }
        { const float4 v = col[1 ^ h]; a2[2] = v2f{v.x, v.y}; a2[3] = v2f{v.z, v.w}; }
        { const float4 v = col[2 ^ h]; a2[4] = v2f{v.x, v.y}; a2[5] = v2f{v.z, v.w}; }
        { const float4 v = col[3 ^ h]; a2[6] = v2f{v.x, v.y}; a2[7] = v2f{v.z, v.w}; }
      }
      {
        const int cj = cidx[j1];
        const int h  = (cj ^ (cj >> 2)) & 3;
        const float4* col = plane4 + cj * 4;
        { const float4 v = col[0 ^ h]; b2[0] = v2f{v.x, v.y}; b2[1] = v2f{v.z, v.w}; }
        { const float4 v = col[1 ^ h]; b2[2] = v2f{v.x, v.y}; b2[3] = v2f{v.z, v.w}; }
        { const float4 v = col[2 ^ h]; b2[4] = v2f{v.x, v.y}; b2[5] = v2f{v.z, v.w}; }
        { const float4 v = col[3 ^ h]; b2[6] = v2f{v.x, v.y}; b2[7] = v2f{v.z, v.w}; }
      }

      // ---- forward substitution: L columns 0..j0-1 applied to BOTH ----
      // (k<j0 folds at compile time; each L2[k][m] read once, used twice)
#pragma unroll
      for (int k = 0; k < NE - 2; ++k) {
        if (k < j0) {
          const float ua = (k & 1) ? a2[k >> 1].y : a2[k >> 1].x;
          const float ub = (k & 1) ? b2[k >> 1].y : b2[k >> 1].x;
          const v2f uav = {ua, ua};
          const v2f ubv = {ub, ub};
#pragma unroll
          for (int m = k >> 1; m < 8; ++m) {
            const v2f l = L2[k][m];
            a2[m] = __builtin_elementwise_fma(-l, uav, a2[m]);
            b2[m] = __builtin_elementwise_fma(-l, ubv, b2[m]);
          }
        }
      }

      // ---- pivot j0, form L col j0 (from VGPR-live a2), apply to b ----
      const float p0 = a2[t].x;
      det *= p0;
      float r0 = __builtin_amdgcn_rcpf(p0);
      r0 = r0 * fmaf(-p0, r0, 2.0f);            // one Newton step: ~1 ulp
      const v2f r0v = {r0, r0};
      const float ub0 = b2[t].x;
      const v2f w0v = {r0 * ub0, r0 * ub0};
#pragma unroll
      for (int m = t; m < 8; ++m) {
        if (t < 7) L2[j0][m] = a2[m] * r0v;     // skip col 14 (in-pair only)
        b2[m] = __builtin_elementwise_fma(-a2[m], w0v, b2[m]);
      }

      // ---- pivot j1, form L col j1 (skip col 15) ----
      const float p1 = b2[t].y;
      det *= p1;
      if (t < 7) {
        float r1 = __builtin_amdgcn_rcpf(p1);
        r1 = r1 * fmaf(-p1, r1, 2.0f);
        const v2f r1v = {r1, r1};
#pragma unroll
        for (int m = t; m < 8; ++m)
          L2[j1][m] = b2[m] * r1v;
      }
    }
    result *= det;
  }

  // out[s*128 + c]
  out[(blockIdx.x * 2 + s_local) * NCONF + c] = result;
}

extern "C" void kernel_launch(void* const* d_in, const int* in_sizes, int n_in,
                              void* d_out, int out_size, void* d_ws, size_t ws_size,
                              hipStream_t stream) {
  const float* x   = (const float*)d_in[0];
  const int*   cup = (const int*)d_in[1];
  const int*   cdn = (const int*)d_in[2];
  float*       out = (float*)d_out;

  dim3 grid(NSAMP / 2), block(256);   // 1024 blocks, 2 samples each
  hipLaunchKernelGGL(SlaterPooling_45543833207162_kernel, grid, block, 0, stream,
                     x, cup, cdn, out);
}

// Round 17
// 24.052 us; speedup vs baseline: 1.2279x; 1.2279x over previous
//
#include <hip/hip_runtime.h>

#define NSAMP 2048
#define NCONF 128
#define NMO   64
#define NE    16   // electrons per spin (matrix dim)

typedef float v2f __attribute__((ext_vector_type(2)));

// ROUND-15 KERNEL, VERBATIM (best measured: 23.9 us, absmax 2.2e13 = 2.3x
// margin). Round 16's 2-column panel regressed (29.5 us, margin 1.45x):
// the in-pair apply added a serial chain segment and the predicated store
// broke codegen. Reverted per post-mortem discipline.
//
// Block = 256 threads = 2 samples x 128 configs.
// LDS: samples staged TRANSPOSED (column-major per (sample,spin) plane) with
// XOR swizzle on the 16B slot: word(c,r)=c*16+(((r>>2)^h(c))<<2)|(r&3),
// h(c)=(c^(c>>2))&3. One matrix column = 4 x ds_read_b128.
//
// Per thread: det(up)*det(dn) via LEFT-LOOKING UNPIVOTED LU (Crout),
// PACKED-FP32: column a and L rows held as float2 ext-vectors;
// __builtin_elementwise_fma lowers to v_pk_fma_f32 (2 FMA/instr).
// ~650 packed FMA/spin replaces ~1240 scalar FMA. Full-pair updates;
// every corrupted slot had its multiplier extracted beforehand and holds
// finite garbage -> numerics = scalar LU up to rounding order.
// (256,1) mandatory: 9 attempts at higher occupancy all spilled.
__global__ __launch_bounds__(256, 1)
void SlaterPooling_45543833207162_kernel(const float* __restrict__ x,
                                         const int*   __restrict__ cup,
                                         const int*   __restrict__ cdn,
                                         float*       __restrict__ out) {
  __shared__ float tile[4 * 64 * NE];   // 4 planes x 64 cols x 16 rows = 16 KB
  float4* tile4 = reinterpret_cast<float4*>(tile);

  // ---- stage 16 KB coalesced; write transposed + swizzled ----
  {
    const float4* src = reinterpret_cast<const float4*>(
        x + (size_t)blockIdx.x * 2 * (2 * NE * NMO));
#pragma unroll
    for (int k = 0; k < 4; ++k) {
      const int   f4 = threadIdx.x + k * 256;   // float4 index in block region
      const float4 v = src[f4];
      const int flat  = f4 * 4;                 // word index (row-major global)
      const int plane = flat >> 10;             // (s_local, spin) plane 0..3
      const int r     = (flat >> 6) & 15;       // row within plane
      const int c4    = (flat >> 2) & 15;       // c = 4*c4 + d
      const int rlo = r & 3, rhi = r >> 2;
      const float vv[4] = {v.x, v.y, v.z, v.w};
#pragma unroll
      for (int d = 0; d < 4; ++d) {
        const int cc = 4 * c4 + d;
        const int h  = (d ^ c4) & 3;            // == (cc ^ (cc>>2)) & 3
        tile[plane * 1024 + cc * NE + (((rhi ^ h) << 2) | rlo)] = vv[d];
      }
    }
  }
  __syncthreads();

  const int s_local = threadIdx.x >> 7;         // 0..1
  const int c       = threadIdx.x & 127;        // config index
  float result = 1.0f;

  // spin loop NOT unrolled: L2 and column regs reused across spins
#pragma unroll 1
  for (int spin = 0; spin < 2; ++spin) {
    // ---- config indices: 4 x int4, hoisted out of the column loop ----
    const int4* cfg4 = reinterpret_cast<const int4*>(
        (spin ? cdn : cup) + c * NE);
    const int4 q0 = cfg4[0], q1 = cfg4[1], q2 = cfg4[2], q3 = cfg4[3];
    const int cidx[16] = {q0.x, q0.y, q0.z, q0.w,  q1.x, q1.y, q1.z, q1.w,
                          q2.x, q2.y, q2.z, q2.w,  q3.x, q3.y, q3.z, q3.w};

    const float4* plane4 = tile4 + (s_local * 2 + spin) * 256;

    v2f L2[NE - 1][8];   // L column k lives in pairs m = k>>1 .. 7
    float det = 1.0f;    // no pivoting -> no sign correction

#pragma unroll
    for (int j = 0; j < NE; ++j) {
      // ---- column j: 4 x ds_read_b128 from the swizzled plane ----
      const int cj = cidx[j];
      const int h  = (cj ^ (cj >> 2)) & 3;
      const float4* col = plane4 + cj * 4;
      v2f a2[8];
      { const float4 t = col[0 ^ h]; a2[0] = v2f{t.x, t.y}; a2[1] = v2f{t.z, t.w}; }
      { const float4 t = col[1 ^ h]; a2[2] = v2f{t.x, t.y}; a2[3] = v2f{t.z, t.w}; }
      { const float4 t = col[2 ^ h]; a2[4] = v2f{t.x, t.y}; a2[5] = v2f{t.z, t.w}; }
      { const float4 t = col[3 ^ h]; a2[6] = v2f{t.x, t.y}; a2[7] = v2f{t.z, t.w}; }

      // ---- forward substitution through L columns 0..j-1 (packed) ----
      // (k<j folds at compile time; full-pair FMAs, dead slots harmless)
#pragma unroll
      for (int k = 0; k < NE - 1; ++k) {
        if (k < j) {
          const float uk = (k & 1) ? a2[k >> 1].y : a2[k >> 1].x;
          const v2f ukv = {uk, uk};
#pragma unroll
          for (int m = k >> 1; m < 8; ++m)
            a2[m] = __builtin_elementwise_fma(-L2[k][m], ukv, a2[m]);
        }
      }

      // ---- pivot, det update, form L column j (packed scale) ----
      const float p = (j & 1) ? a2[j >> 1].y : a2[j >> 1].x;
      det *= p;
      if (j < NE - 1) {
        float r = __builtin_amdgcn_rcpf(p);
        r = r * fmaf(-p, r, 2.0f);              // one Newton step: ~1 ulp
        const v2f rv = {r, r};
#pragma unroll
        for (int m = j >> 1; m < 8; ++m)
          L2[j][m] = a2[m] * rv;
      }
    }
    result *= det;
  }

  // out[s*128 + c]
  out[(blockIdx.x * 2 + s_local) * NCONF + c] = result;
}

extern "C" void kernel_launch(void* const* d_in, const int* in_sizes, int n_in,
                              void* d_out, int out_size, void* d_ws, size_t ws_size,
                              hipStream_t stream) {
  const float* x   = (const float*)d_in[0];
  const int*   cup = (const int*)d_in[1];
  const int*   cdn = (const int*)d_in[2];
  float*       out = (float*)d_out;

  dim3 grid(NSAMP / 2), block(256);   // 1024 blocks, 2 samples each
  hipLaunchKernelGGL(SlaterPooling_45543833207162_kernel, grid, block, 0, stream,
                     x, cup, cdn, out);
}

// Round 18
// 23.984 us; speedup vs baseline: 1.2313x; 1.0028x over previous
//
#include <hip/hip_runtime.h>

#define NSAMP 2048
#define NCONF 128
#define NMO   64
#define NE    16   // electrons per spin (matrix dim)

typedef float v2f __attribute__((ext_vector_type(2)));

// Round-15 structure (23.9 us), single micro-change: Newton refinement on
// v_rcp_f32 REMOVED. gfx950 rcp is ~1 ulp; the 2 dependent FMAs sat on the
// serial pivot chain 32x per det-pair (~4-7% of critical path) refining
// noise far below the unpivoted-LU growth error that dominates absmax.
//
// Block = 256 threads = 2 samples x 128 configs.
// LDS: samples staged TRANSPOSED (column-major per (sample,spin) plane) with
// XOR swizzle on the 16B slot: word(c,r)=c*16+(((r>>2)^h(c))<<2)|(r&3),
// h(c)=(c^(c>>2))&3. One matrix column = 4 x ds_read_b128.
//
// Per thread: det(up)*det(dn) via LEFT-LOOKING UNPIVOTED LU (Crout),
// PACKED-FP32 (v_pk_fma_f32): ~650 packed FMA/spin. Full-pair updates;
// corrupted slots are dead (multiplier extracted beforehand) and finite.
// (256,1) mandatory: 9 higher-occupancy attempts spilled; 2-col panel
// regressed (r16). This shape is the allocator's fixed point.
__global__ __launch_bounds__(256, 1)
void SlaterPooling_45543833207162_kernel(const float* __restrict__ x,
                                         const int*   __restrict__ cup,
                                         const int*   __restrict__ cdn,
                                         float*       __restrict__ out) {
  __shared__ float tile[4 * 64 * NE];   // 4 planes x 64 cols x 16 rows = 16 KB
  float4* tile4 = reinterpret_cast<float4*>(tile);

  // ---- stage 16 KB coalesced; write transposed + swizzled ----
  {
    const float4* src = reinterpret_cast<const float4*>(
        x + (size_t)blockIdx.x * 2 * (2 * NE * NMO));
#pragma unroll
    for (int k = 0; k < 4; ++k) {
      const int   f4 = threadIdx.x + k * 256;   // float4 index in block region
      const float4 v = src[f4];
      const int flat  = f4 * 4;                 // word index (row-major global)
      const int plane = flat >> 10;             // (s_local, spin) plane 0..3
      const int r     = (flat >> 6) & 15;       // row within plane
      const int c4    = (flat >> 2) & 15;       // c = 4*c4 + d
      const int rlo = r & 3, rhi = r >> 2;
      const float vv[4] = {v.x, v.y, v.z, v.w};
#pragma unroll
      for (int d = 0; d < 4; ++d) {
        const int cc = 4 * c4 + d;
        const int h  = (d ^ c4) & 3;            // == (cc ^ (cc>>2)) & 3
        tile[plane * 1024 + cc * NE + (((rhi ^ h) << 2) | rlo)] = vv[d];
      }
    }
  }
  __syncthreads();

  const int s_local = threadIdx.x >> 7;         // 0..1
  const int c       = threadIdx.x & 127;        // config index
  float result = 1.0f;

  // spin loop NOT unrolled: L2 and column regs reused across spins
#pragma unroll 1
  for (int spin = 0; spin < 2; ++spin) {
    // ---- config indices: 4 x int4, hoisted out of the column loop ----
    const int4* cfg4 = reinterpret_cast<const int4*>(
        (spin ? cdn : cup) + c * NE);
    const int4 q0 = cfg4[0], q1 = cfg4[1], q2 = cfg4[2], q3 = cfg4[3];
    const int cidx[16] = {q0.x, q0.y, q0.z, q0.w,  q1.x, q1.y, q1.z, q1.w,
                          q2.x, q2.y, q2.z, q2.w,  q3.x, q3.y, q3.z, q3.w};

    const float4* plane4 = tile4 + (s_local * 2 + spin) * 256;

    v2f L2[NE - 1][8];   // L column k lives in pairs m = k>>1 .. 7
    float det = 1.0f;    // no pivoting -> no sign correction

#pragma unroll
    for (int j = 0; j < NE; ++j) {
      // ---- column j: 4 x ds_read_b128 from the swizzled plane ----
      const int cj = cidx[j];
      const int h  = (cj ^ (cj >> 2)) & 3;
      const float4* col = plane4 + cj * 4;
      v2f a2[8];
      { const float4 t = col[0 ^ h]; a2[0] = v2f{t.x, t.y}; a2[1] = v2f{t.z, t.w}; }
      { const float4 t = col[1 ^ h]; a2[2] = v2f{t.x, t.y}; a2[3] = v2f{t.z, t.w}; }
      { const float4 t = col[2 ^ h]; a2[4] = v2f{t.x, t.y}; a2[5] = v2f{t.z, t.w}; }
      { const float4 t = col[3 ^ h]; a2[6] = v2f{t.x, t.y}; a2[7] = v2f{t.z, t.w}; }

      // ---- forward substitution through L columns 0..j-1 (packed) ----
      // (k<j folds at compile time; full-pair FMAs, dead slots harmless)
#pragma unroll
      for (int k = 0; k < NE - 1; ++k) {
        if (k < j) {
          const float uk = (k & 1) ? a2[k >> 1].y : a2[k >> 1].x;
          const v2f ukv = {uk, uk};
#pragma unroll
          for (int m = k >> 1; m < 8; ++m)
            a2[m] = __builtin_elementwise_fma(-L2[k][m], ukv, a2[m]);
        }
      }

      // ---- pivot, det update, form L column j (packed scale) ----
      const float p = (j & 1) ? a2[j >> 1].y : a2[j >> 1].x;
      det *= p;
      if (j < NE - 1) {
        const float r = __builtin_amdgcn_rcpf(p);   // ~1 ulp; Newton removed
        const v2f rv = {r, r};
#pragma unroll
        for (int m = j >> 1; m < 8; ++m)
          L2[j][m] = a2[m] * rv;
      }
    }
    result *= det;
  }

  // out[s*128 + c]
  out[(blockIdx.x * 2 + s_local) * NCONF + c] = result;
}

extern "C" void kernel_launch(void* const* d_in, const int* in_sizes, int n_in,
                              void* d_out, int out_size, void* d_ws, size_t ws_size,
                              hipStream_t stream) {
  const float* x   = (const float*)d_in[0];
  const int*   cup = (const int*)d_in[1];
  const int*   cdn = (const int*)d_in[2];
  float*       out = (float*)d_out;

  dim3 grid(NSAMP / 2), block(256);   // 1024 blocks, 2 samples each
  hipLaunchKernelGGL(SlaterPooling_45543833207162_kernel, grid, block, 0, stream,
                     x, cup, cdn, out);
}